// Round 15
// baseline (388.023 us; speedup 1.0000x reference)
//
#include <hip/hip_runtime.h>
#include <hip/hip_bf16.h>

#define B_ 16
#define S_ 1024
#define D_ 512
#define H_ 8
#define DH_ 64

typedef __attribute__((ext_vector_type(8))) short bf16x8;
typedef __attribute__((ext_vector_type(4))) short bf16x4;
typedef __attribute__((ext_vector_type(4))) float f32x4;
typedef __attribute__((ext_vector_type(16))) float f32x16;

__device__ __forceinline__ short f2bf(float f) {
    __hip_bfloat16 h = __float2bfloat16(f);
    return *reinterpret_cast<short*>(&h);
}
__device__ __forceinline__ float bf2f(short s) {
    unsigned u = ((unsigned)(unsigned short)s) << 16;
    return __uint_as_float(u);
}
__device__ __forceinline__ unsigned pack_bf2(float lo, float hi) {
    unsigned a = (unsigned)(unsigned short)f2bf(lo);
    unsigned b = (unsigned)(unsigned short)f2bf(hi);
    return a | (b << 16);
}
__device__ __forceinline__ void gload16(const void* g, void* l) {
    __builtin_amdgcn_global_load_lds(
        (const __attribute__((address_space(1))) unsigned int*)g,
        (__attribute__((address_space(3))) unsigned int*)l, 16, 0, 0);
}

// ---------------------------------------------------------------------------
// prep_w: blocks 0..511 convert Wq/Wk/Wv/Wo to bf16 (Wq pre-scaled by
// 0.125*log2e); blocks 512..767 MT = M^T bf16 via LDS tile transpose.
// ---------------------------------------------------------------------------
__global__ __launch_bounds__(256) void prep_w(
    const float* __restrict__ M, const float* __restrict__ Wq,
    const float* __restrict__ Wk, const float* __restrict__ Wv,
    const float* __restrict__ Wo, __hip_bfloat16* __restrict__ wb)
{
    __hip_bfloat16* wsrc = wb;                 // 1536*512
    __hip_bfloat16* Wob  = wb + 786432;        // 512*512
    __hip_bfloat16* MT   = wb + 1048576;       // 512*512

    const int blk = blockIdx.x, t = threadIdx.x;
    if (blk < 512) {
        const int wi = blk >> 7;               // 0:Wq 1:Wk 2:Wv 3:Wo
        const int off = (blk & 127) * 2048 + t * 8;
        const float* src = (wi == 0) ? Wq : (wi == 1) ? Wk : (wi == 2) ? Wv : Wo;
        const float scale = (wi == 0) ? 0.18033688011112042f : 1.0f;
        const float4 f0 = *reinterpret_cast<const float4*>(src + off);
        const float4 f1 = *reinterpret_cast<const float4*>(src + off + 4);
        const float fv[8] = {f0.x, f0.y, f0.z, f0.w, f1.x, f1.y, f1.z, f1.w};
        union { short s[8]; bf16x8 v; } r;
#pragma unroll
        for (int j = 0; j < 8; ++j) r.s[j] = f2bf(fv[j] * scale);
        __hip_bfloat16* dst = (wi == 3) ? (Wob + off) : (wsrc + wi * 262144 + off);
        *reinterpret_cast<bf16x8*>(dst) = r.v;
    } else {
        __shared__ float tile[32][33];
        const int tt = blk - 512;              // 256 tiles
        const int e0 = (tt & 15) * 32, d0 = (tt >> 4) * 32;
        const int r = t >> 5, c = t & 31;
#pragma unroll
        for (int k = 0; k < 4; ++k)
            tile[r + k * 8][c] = M[(size_t)(e0 + r + k * 8) * 512 + d0 + c];
        __syncthreads();
#pragma unroll
        for (int k = 0; k < 4; ++k)
            MT[(size_t)(d0 + r + k * 8) * 512 + e0 + c] =
                __float2bfloat16(tile[c][r + k * 8]);
    }
}

// ---------------------------------------------------------------------------
// bias_k: qkvpart[dc][w*16+b][n] over 4 d-chunks of 128.
// ---------------------------------------------------------------------------
__global__ __launch_bounds__(256) void bias_k(
    const __hip_bfloat16* __restrict__ wsrc, const float* __restrict__ ts_emb,
    const int* __restrict__ te, float* __restrict__ qkvpart)
{
    const int blk = blockIdx.x;
    const int w16b = blk >> 2, dc = blk & 3;
    const int b = w16b & 15, w = w16b >> 4;
    const float* e = ts_emb + (size_t)te[b] * 512 + dc * 128;
#pragma unroll
    for (int rep = 0; rep < 2; ++rep) {
        const int n = threadIdx.x + rep * 256;
        const __hip_bfloat16* wr = wsrc + ((size_t)(w * 512 + n)) * 512 + dc * 128;
        float s = 0.f;
#pragma unroll 4
        for (int d8 = 0; d8 < 128; d8 += 8) {
            const bf16x8 wv8 = *reinterpret_cast<const bf16x8*>(wr + d8);
            const float4 e0 = *reinterpret_cast<const float4*>(e + d8);
            const float4 e1 = *reinterpret_cast<const float4*>(e + d8 + 4);
            s += bf2f(wv8[0]) * e0.x + bf2f(wv8[1]) * e0.y
               + bf2f(wv8[2]) * e0.z + bf2f(wv8[3]) * e0.w
               + bf2f(wv8[4]) * e1.x + bf2f(wv8[5]) * e1.y
               + bf2f(wv8[6]) * e1.z + bf2f(wv8[7]) * e1.w;
        }
        qkvpart[(size_t)dc * 24576 + (size_t)w16b * 512 + n] = s;
    }
}

// ---------------------------------------------------------------------------
// K1: conv1d + bias + pos-emb + GELU + LN -> n1 bf16 (B*S,512).
// ---------------------------------------------------------------------------
__global__ __launch_bounds__(256) void k1_conv_gelu_ln(
    const float* __restrict__ ts, const float* __restrict__ conv_w,
    const float* __restrict__ conv_b, const float* __restrict__ pe,
    const float* __restrict__ g1, const float* __restrict__ b1,
    __hip_bfloat16* __restrict__ n1)
{
    const int w = threadIdx.x >> 6, lane = threadIdx.x & 63;
    const int row = blockIdx.x * 4 + w;      // b*S + s
    const int b = row >> 10, s = row & 1023;
    const float4 x = *reinterpret_cast<const float4*>(ts + b * 4096 + s * 4);
    const int d0 = lane * 8;

    const float4 cb0 = *reinterpret_cast<const float4*>(conv_b + d0);
    const float4 cb1 = *reinterpret_cast<const float4*>(conv_b + d0 + 4);
    const float4 pe0 = *reinterpret_cast<const float4*>(pe + s * 512 + d0);
    const float4 pe1 = *reinterpret_cast<const float4*>(pe + s * 512 + d0 + 4);
    const float cbv[8] = {cb0.x, cb0.y, cb0.z, cb0.w, cb1.x, cb1.y, cb1.z, cb1.w};
    const float pev[8] = {pe0.x, pe0.y, pe0.z, pe0.w, pe1.x, pe1.y, pe1.z, pe1.w};

    float a[8];
    float sum = 0.f, sq = 0.f;
#pragma unroll
    for (int j = 0; j < 8; ++j) {
        const float4 wv = *reinterpret_cast<const float4*>(conv_w + (d0 + j) * 4);
        float v = x.x * wv.x + x.y * wv.y + x.z * wv.z + x.w * wv.w
                + cbv[j] + pev[j];
        v = 0.5f * v * (1.0f + erff(v * 0.70710678118654752f));
        a[j] = v; sum += v; sq += v * v;
    }
#pragma unroll
    for (int off = 1; off < 64; off <<= 1) {
        sum += __shfl_xor(sum, off);
        sq  += __shfl_xor(sq, off);
    }
    const float mean = sum * (1.0f / 512.0f);
    const float var  = (sq - 512.0f * mean * mean) * (1.0f / 511.0f);
    const float rstd = rsqrtf(var + 1e-5f);
    const float gg = g1[s], bb = b1[s];
    union { short sh[8]; bf16x8 v; } o;
#pragma unroll
    for (int j = 0; j < 8; ++j)
        o.sh[j] = f2bf(gg * ((a[j] - mean) * rstd) + bb);
    *reinterpret_cast<bf16x8*>(n1 + (size_t)row * 512 + d0) = o.v;
}

// ---------------------------------------------------------------------------
// GEMM: out[r][n] = sum_d A[r][d] * Wb[n][d]  (bf16 x bf16, K=512)
// BM=128 BN=128 BK=64, 4 waves (2x2). Double-buffered LDS, 2-phase.
// MODE 3: += bo[n], bf16 row-major (Wo);  MODE 5: fused QKV;
// MODE 6: plain bf16 row-major (weight compose)
// ---------------------------------------------------------------------------
template<int MODE>
__global__ __launch_bounds__(256, 2) void gemm_k(
    const __hip_bfloat16* __restrict__ A,
    const __hip_bfloat16* __restrict__ Wb,
    void* __restrict__ outp,
    const float* __restrict__ aux)
{
    __shared__ char lA[2][128 * 128];
    __shared__ char lB[2][128 * 128];

    const int t = threadIdx.x;
    const int lane = t & 63;
    const int w = t >> 6;
    const int wm = w & 1, wn = w >> 1;
    const int Rb = blockIdx.x * 128;
    const int Nb = blockIdx.y * 128;
    const int g = lane >> 4, lr = lane & 15;
    const int lrow = lane >> 3;
    const int coff = ((lane & 7) ^ lrow) * 8;

    const __hip_bfloat16* asrc = A  + (size_t)(Rb + lrow) * 512 + coff;
    const __hip_bfloat16* bsrc = Wb + (size_t)(Nb + lrow) * 512 + coff;

    f32x4 acc[4][4];
#pragma unroll
    for (int i = 0; i < 4; ++i)
#pragma unroll
        for (int j = 0; j < 4; ++j) acc[i][j] = {0.f, 0.f, 0.f, 0.f};

    auto stage = [&](int buf, int k0) {
#pragma unroll
        for (int i = 0; i < 4; ++i) {
            const int r0 = w * 32 + i * 8;
            gload16(asrc + (size_t)r0 * 512 + k0, &lA[buf][r0 * 128]);
        }
#pragma unroll
        for (int i = 0; i < 4; ++i) {
            const int r0 = w * 32 + i * 8;
            gload16(bsrc + (size_t)r0 * 512 + k0, &lB[buf][r0 * 128]);
        }
    };

    stage(0, 0);
    __syncthreads();

    for (int kt = 0; kt < 8; ++kt) {
        const int buf = kt & 1;
        if (kt < 7) stage(buf ^ 1, (kt + 1) * 64);
#pragma unroll
        for (int kk = 0; kk < 2; ++kk) {
            bf16x8 af[4], bfv[4];
            const int ch = kk * 4 + g;
#pragma unroll
            for (int mt = 0; mt < 4; ++mt) {
                const int row = wm * 64 + mt * 16 + lr;
                af[mt] = *reinterpret_cast<const bf16x8*>(
                    &lA[buf][row * 128 + ((ch ^ (row & 7)) << 4)]);
            }
#pragma unroll
            for (int nt = 0; nt < 4; ++nt) {
                const int row = wn * 64 + nt * 16 + lr;
                bfv[nt] = *reinterpret_cast<const bf16x8*>(
                    &lB[buf][row * 128 + ((ch ^ (row & 7)) << 4)]);
            }
#pragma unroll
            for (int mt = 0; mt < 4; ++mt)
#pragma unroll
                for (int nt = 0; nt < 4; ++nt)
                    acc[mt][nt] = __builtin_amdgcn_mfma_f32_16x16x32_bf16(
                        af[mt], bfv[nt], acc[mt][nt], 0, 0, 0);
        }
        __syncthreads();
    }

    const int w3 = Nb >> 9;   // block-uniform (MODE 5)
#pragma unroll
    for (int mt = 0; mt < 4; ++mt) {
#pragma unroll
        for (int nt = 0; nt < 4; ++nt) {
#pragma unroll
            for (int r = 0; r < 4; ++r) {
                const int R = Rb + wm * 64 + mt * 16 + 4 * g + r;
                const int N = Nb + wn * 64 + nt * 16 + lr;
                float v = acc[mt][nt][r];
                if (MODE == 5) {
                    const int Nl = N & 511;
                    const int b = R >> 10, s = R & 1023, h = Nl >> 6, c = Nl & 63;
                    const float* qp = aux + (size_t)(w3 * 16 + b) * 512 + Nl;
                    v += qp[0] + qp[24576] + qp[49152] + qp[73728];
                    __hip_bfloat16* base =
                        reinterpret_cast<__hip_bfloat16*>(outp) + (size_t)w3 * 8388608;
                    if (w3 == 2)
                        base[(((size_t)(b * 8 + h)) * 64 + c) * 1024 + s] =
                            __float2bfloat16(v);
                    else
                        base[(((size_t)(b * 8 + h)) * 1024 + s) * 64 + c] =
                            __float2bfloat16(v);
                } else if (MODE == 6) {
                    reinterpret_cast<__hip_bfloat16*>(outp)[(size_t)R * 512 + N] =
                        __float2bfloat16(v);
                } else {
                    reinterpret_cast<__hip_bfloat16*>(outp)[(size_t)R * 512 + N] =
                        __float2bfloat16(v + aux[N]);
                }
            }
        }
    }
}

// ---------------------------------------------------------------------------
// Flash attention attn7: attn5 structure + IN-BLOCK i-SPLIT.
// Block = 512 threads / 8 waves: waves 0-3 (half A) cover i-tiles [0,mid),
// waves 4-7 (half B) cover [mid,T), T = jb*4+4, mid = T/2 (equal halves).
// Each half has its own 16KB double-buffered Q/V staging (shared within the
// half) -> FETCH unchanged vs attn5, but 2x waves per j-strip -> 32 waves/CU.
// Partials merged in-LDS (r6-verified online-softmax combine), A writes.
// ---------------------------------------------------------------------------
__device__ __forceinline__ void write_strip(
    __hip_bfloat16* __restrict__ dstbase, const int jw0,
    const f32x16& o0, const f32x16& o1, const float lsum,
    const int l5, const int ln31)
{
    const float linv = 1.0f / lsum;
#pragma unroll
    for (int r = 0; r < 16; ++r) {
        const int jrow = (r & 3) + 8 * (r >> 2) + 4 * l5;
        const float rinv = __shfl(linv, jrow);
        __hip_bfloat16* dst = dstbase + (size_t)(jw0 + jrow) * 512;
        dst[ln31]      = __float2bfloat16(o0[r] * rinv);
        dst[32 + ln31] = __float2bfloat16(o1[r] * rinv);
    }
}

__global__ __launch_bounds__(512, 6) void attn7_k(
    const __hip_bfloat16* __restrict__ Qm,   // (B,H,S,64), pre-scaled
    const __hip_bfloat16* __restrict__ Km,   // (B,H,S,64)
    const __hip_bfloat16* __restrict__ Vt,   // (B,H,64,S)
    __hip_bfloat16* __restrict__ cat)        // (B,S,512)
{
    __shared__ char smem[35072];   // [0,32K): 2 halves x (qbuf 8K + vbuf 8K)
                                   // after final barrier reused as merge buf

    const int t = threadIdx.x, lane = t & 63, w = t >> 6;
    const int l5 = lane >> 5, ln31 = lane & 31;
    const int half = w >> 2, wloc = w & 3;
    const int th = t & 255;                  // thread index within half
    const int sw = th >> 6;                  // wave-in-half (== wloc)
    const int id = blockIdx.x;
    const int bh = id & 127;
    const int jb = (0x32451067u >> ((id >> 7) * 4)) & 7;
    const int b = bh >> 3, h = bh & 7;
    const int j0 = jb * 128 + wloc * 32;

    const __hip_bfloat16* Qh = Qm + (size_t)bh * (S_ * 64);
    const __hip_bfloat16* Kh = Km + (size_t)bh * (S_ * 64);
    const __hip_bfloat16* Vh = Vt + (size_t)bh * (64 * S_);

    bf16x8 kf[4];
#pragma unroll
    for (int kt = 0; kt < 4; ++kt)
        kf[kt] = *reinterpret_cast<const bf16x8*>(
            Kh + (size_t)(j0 + ln31) * 64 + kt * 16 + l5 * 8);

    f32x16 o0, o1;
#pragma unroll
    for (int r = 0; r < 16; ++r) { o0[r] = 0.f; o1[r] = 0.f; }
    float m = -3e38f, lsum = 0.f;

    const int T = jb * 4 + 4;                // total i-tiles for this j-block
    const int mid = T >> 1;                  // equal split (T even)
    const int lo = half ? mid : 0;
    const int myLast = jb * 4 + wloc;        // wave's diag tile

    // staging constants (within-half threads, lane = th&63)
    const int hl = th & 63;
    const int q_row  = sw * 8 + (hl >> 3);
    const int q_ch   = (hl & 7) ^ (hl >> 3);
    const int v_row  = sw * 16 + (hl >> 2);
    const int v_ch   = (hl & 3) ^ ((hl >> 2) & 3) ^ ((hl >> 4) & 3);
    const __hip_bfloat16* qsrc = Qh + (size_t)q_row * 64 + q_ch * 8;
    const __hip_bfloat16* vsrc = Vh + (size_t)v_row * 1024 + v_ch * 8;
    char* qbase = smem + half * 16384;
    char* vbase = smem + half * 16384 + 8192;

    auto stage = [&](int buf, int tile) {
        const int i0 = tile * 32;
        gload16(qsrc + (size_t)i0 * 64, qbase + buf * 4096 + sw * 1024);
        gload16(vsrc + i0,              vbase + buf * 4096 + sw * 1024);
    };

    stage(0, lo);
    __syncthreads();

    for (int it = 0; it < mid; ++it) {
        const int buf = it & 1;
        const int tile = lo + it;
        if (it + 1 < mid) stage(buf ^ 1, tile + 1);
        if (tile <= myLast) {
            f32x16 sc;
#pragma unroll
            for (int r = 0; r < 16; ++r) sc[r] = 0.f;
            bf16x8 qf[4];
#pragma unroll
            for (int kt = 0; kt < 4; ++kt)
                qf[kt] = *reinterpret_cast<const bf16x8*>(
                    qbase + buf * 4096 + ln31 * 128 + (((kt * 2 + l5) ^ (ln31 & 7)) << 4));
#pragma unroll
            for (int kt = 0; kt < 4; ++kt)
                sc = __builtin_amdgcn_mfma_f32_32x32x16_bf16(qf[kt], kf[kt], sc, 0, 0, 0);

            union u8 { bf16x4 h[2]; bf16x8 v; };
            u8 vf[2][2];
#pragma unroll
            for (int kt = 0; kt < 2; ++kt) {
#pragma unroll
                for (int dh = 0; dh < 2; ++dh) {
                    const int drow = ln31 + dh * 32;
                    const int swz = (drow & 3) ^ ((drow >> 2) & 3);
                    const int x0 = kt * 32 + 8 * l5;
#pragma unroll
                    for (int hp = 0; hp < 2; ++hp) {
                        const int x = x0 + hp * 16;
                        vf[kt][dh].h[hp] = *reinterpret_cast<const bf16x4*>(
                            vbase + buf * 4096 + drow * 64 + (((x >> 4) ^ swz) << 4) + (x & 15));
                    }
                }
            }

            const bool diag = (tile == myLast);
            float p[16];
            float mx = -3e38f;
            if (diag) {
#pragma unroll
                for (int r = 0; r < 16; ++r) {
                    const int irow = (r & 3) + 8 * (r >> 2) + 4 * l5;
                    const float v = (irow > ln31) ? -3e38f : sc[r];
                    p[r] = v; mx = fmaxf(mx, v);
                }
            } else {
#pragma unroll
                for (int r = 0; r < 16; ++r) { p[r] = sc[r]; mx = fmaxf(mx, sc[r]); }
            }
            mx = fmaxf(mx, __shfl_xor(mx, 32));
            if (!__all(mx <= m + 8.0f)) {
                const float mn = fmaxf(m, mx);
                const float alpha = exp2f(m - mn);
                m = mn; lsum *= alpha;
#pragma unroll
                for (int r = 0; r < 16; ++r) {
                    const int jrow = (r & 3) + 8 * (r >> 2) + 4 * l5;
                    const float ar = __shfl(alpha, jrow);
                    o0[r] *= ar; o1[r] *= ar;
                }
            }
            float ps = 0.f;
#pragma unroll
            for (int r = 0; r < 16; ++r) { p[r] = exp2f(p[r] - m); ps += p[r]; }
            ps += __shfl_xor(ps, 32);
            lsum += ps;

            union { unsigned u[4]; bf16x8 v; } pa0, pa1;
            pa0.u[0] = pack_bf2(p[0],  p[1]);  pa0.u[1] = pack_bf2(p[2],  p[3]);
            pa0.u[2] = pack_bf2(p[4],  p[5]);  pa0.u[3] = pack_bf2(p[6],  p[7]);
            pa1.u[0] = pack_bf2(p[8],  p[9]);  pa1.u[1] = pack_bf2(p[10], p[11]);
            pa1.u[2] = pack_bf2(p[12], p[13]); pa1.u[3] = pack_bf2(p[14], p[15]);
            o0 = __builtin_amdgcn_mfma_f32_32x32x16_bf16(pa0.v, vf[0][0].v, o0, 0, 0, 0);
            o1 = __builtin_amdgcn_mfma_f32_32x32x16_bf16(pa0.v, vf[0][1].v, o1, 0, 0, 0);
            o0 = __builtin_amdgcn_mfma_f32_32x32x16_bf16(pa1.v, vf[1][0].v, o0, 0, 0, 0);
            o1 = __builtin_amdgcn_mfma_f32_32x32x16_bf16(pa1.v, vf[1][1].v, o1, 0, 0, 0);
        }
        __syncthreads();
    }

    // ---- merge halves (LDS reused; all staging reads complete) ----------
    float* mrg = (float*)smem;               // [4 waves][64 lanes][34]
    if (half) {
        float* mb = mrg + (wloc * 64 + lane) * 34;
#pragma unroll
        for (int r = 0; r < 16; ++r) { mb[r] = o0[r]; mb[16 + r] = o1[r]; }
        mb[32] = m; mb[33] = lsum;
    }
    __syncthreads();
    if (!half) {
        const float* mb = mrg + (wloc * 64 + lane) * 34;
        const float m1 = mb[32], l1 = mb[33];
        const float ms = fmaxf(m, m1);
        const float a0 = exp2f(m - ms);
        const float a1 = exp2f(m1 - ms);
        lsum = lsum * a0 + l1 * a1;
#pragma unroll
        for (int r = 0; r < 16; ++r) {
            const int jrow = (r & 3) + 8 * (r >> 2) + 4 * l5;
            const float ar0 = __shfl(a0, jrow);
            const float ar1 = __shfl(a1, jrow);
            o0[r] = o0[r] * ar0 + mb[r]      * ar1;
            o1[r] = o1[r] * ar0 + mb[16 + r] * ar1;
        }
        __hip_bfloat16* dstbase = cat + (size_t)b * 1024 * 512 + h * 64;
        write_strip(dstbase, j0, o0, o1, lsum, l5, ln31);
    }
}

// ---------------------------------------------------------------------------
// K5: residual (recompute conv) + LayerNorm over D, transposed store.
// ---------------------------------------------------------------------------
__global__ __launch_bounds__(256) void k5_res_ln(
    const __hip_bfloat16* __restrict__ outf,
    const float* __restrict__ ts, const float* __restrict__ conv_w,
    const float* __restrict__ conv_b, const float* __restrict__ pe,
    const float* __restrict__ g2, const float* __restrict__ b2,
    float* __restrict__ out)         // (B,512,1024)
{
    __shared__ float tile[16 * 520];
    const int blk = blockIdx.x;
    const int b = blk >> 6, s0 = (blk & 63) * 16;
    const int t = threadIdx.x;
    const int sl = t >> 4, c = t & 15;
    const int s = s0 + sl;

    const float4 x = *reinterpret_cast<const float4*>(ts + b * 4096 + s * 4);
    float vals[32];
    float sum = 0.f, sq = 0.f;
#pragma unroll
    for (int j = 0; j < 32; ++j) {
        const int d = c + 16 * j;
        const float4 wv = *reinterpret_cast<const float4*>(conv_w + d * 4);
        const float conv = x.x * wv.x + x.y * wv.y + x.z * wv.z + x.w * wv.w
                         + conv_b[d] + pe[s * 512 + d];
        const float a = __bfloat162float(outf[(size_t)(b * 1024 + s) * 512 + d]) + conv;
        vals[j] = a; sum += a; sq += a * a;
    }
#pragma unroll
    for (int off = 1; off < 16; off <<= 1) {
        sum += __shfl_xor(sum, off);
        sq  += __shfl_xor(sq, off);
    }
    const float mean = sum * (1.0f / 512.0f);
    const float var  = (sq - 512.0f * mean * mean) * (1.0f / 511.0f);
    const float rstd = rsqrtf(var + 1e-5f);
    const float gg = g2[s], bb = b2[s];
#pragma unroll
    for (int j = 0; j < 32; ++j) {
        const int d = c + 16 * j;
        tile[sl * 520 + d] = gg * ((vals[j] - mean) * rstd) + bb;
    }
    __syncthreads();
#pragma unroll
    for (int q2 = 0; q2 < 2; ++q2) {
        const int d = t + q2 * 256;
        float buf[16];
#pragma unroll
        for (int sl2 = 0; sl2 < 16; ++sl2) buf[sl2] = tile[sl2 * 520 + d];
        float4* dst = reinterpret_cast<float4*>(
            out + ((size_t)b * 512 + d) * 1024 + s0);
        dst[0] = make_float4(buf[0],  buf[1],  buf[2],  buf[3]);
        dst[1] = make_float4(buf[4],  buf[5],  buf[6],  buf[7]);
        dst[2] = make_float4(buf[8],  buf[9],  buf[10], buf[11]);
        dst[3] = make_float4(buf[12], buf[13], buf[14], buf[15]);
    }
}

// ---------------------------------------------------------------------------
extern "C" void kernel_launch(void* const* d_in, const int* in_sizes, int n_in,
                              void* d_out, int out_size, void* d_ws, size_t ws_size,
                              hipStream_t stream)
{
    const float* ts     = (const float*)d_in[0];
    const int*   te     = (const int*)d_in[1];
    const float* conv_w = (const float*)d_in[2];
    const float* conv_b = (const float*)d_in[3];
    const float* pe     = (const float*)d_in[4];
    const float* ts_emb = (const float*)d_in[5];
    const float* g1     = (const float*)d_in[6];
    const float* b1     = (const float*)d_in[7];
    const float* M      = (const float*)d_in[8];
    const float* Wq     = (const float*)d_in[9];
    const float* Wk     = (const float*)d_in[10];
    const float* Wv     = (const float*)d_in[11];
    const float* Wo     = (const float*)d_in[12];
    const float* bo     = (const float*)d_in[13];
    const float* g2     = (const float*)d_in[14];
    const float* b2     = (const float*)d_in[15];

    char* ws = (char*)d_ws;
    __hip_bfloat16* wb     = (__hip_bfloat16*)(ws);                 // 3MB @0
    __hip_bfloat16* wsrc   = wb;                                    // 1536x512
    __hip_bfloat16* Wob    = wb + 786432;
    __hip_bfloat16* MT     = wb + 1048576;
    __hip_bfloat16* Wqkvp  = (__hip_bfloat16*)(ws + (2688ull << 10)); // 1.5MB
    float*          qkvpart= (float*)(ws + (4608ull << 10));        // 384KB
    __hip_bfloat16* n1     = (__hip_bfloat16*)(ws + ( 6ull << 20)); // 16MB @6
    __hip_bfloat16* cat    = n1;                                    // reuse @6
    __hip_bfloat16* q      = (__hip_bfloat16*)(ws + (22ull << 20)); // 16MB @22
    __hip_bfloat16* k      = (__hip_bfloat16*)(ws + (38ull << 20)); // 16MB @38
    __hip_bfloat16* vT     = (__hip_bfloat16*)(ws + (54ull << 20)); // 16MB @54
    __hip_bfloat16* outf   = (__hip_bfloat16*)(ws + (22ull << 20)); // 16MB @22 (q dead)

    prep_w<<<768, 256, 0, stream>>>(M, Wq, Wk, Wv, Wo, wb);
    bias_k<<<192, 256, 0, stream>>>(wsrc, ts_emb, te, qkvpart);
    gemm_k<6><<<dim3(12, 4), 256, 0, stream>>>(wsrc, MT, Wqkvp, nullptr);
    k1_conv_gelu_ln<<<4096, 256, 0, stream>>>(ts, conv_w, conv_b, pe, g1, b1, n1);
    gemm_k<5><<<dim3(128, 12), 256, 0, stream>>>(n1, Wqkvp, q, qkvpart);
    attn7_k<<<1024, 512, 0, stream>>>(q, k, vT, cat);
    gemm_k<3><<<dim3(128, 4), 256, 0, stream>>>(cat, Wob, outf, bo);
    k5_res_ln<<<1024, 256, 0, stream>>>(outf, ts, conv_w, conv_b, pe, g2, b2,
                                        (float*)d_out);
}

// Round 16
// 171.808 us; speedup vs baseline: 2.2585x; 2.2585x over previous
//
#include <hip/hip_runtime.h>
#include <hip/hip_bf16.h>

#define B_ 16
#define S_ 1024
#define D_ 512
#define H_ 8
#define DH_ 64

typedef __attribute__((ext_vector_type(8))) short bf16x8;
typedef __attribute__((ext_vector_type(4))) short bf16x4;
typedef __attribute__((ext_vector_type(4))) float f32x4;
typedef __attribute__((ext_vector_type(16))) float f32x16;

__device__ __forceinline__ short f2bf(float f) {
    __hip_bfloat16 h = __float2bfloat16(f);
    return *reinterpret_cast<short*>(&h);
}
__device__ __forceinline__ float bf2f(short s) {
    unsigned u = ((unsigned)(unsigned short)s) << 16;
    return __uint_as_float(u);
}
__device__ __forceinline__ unsigned pack_bf2(float lo, float hi) {
    unsigned a = (unsigned)(unsigned short)f2bf(lo);
    unsigned b = (unsigned)(unsigned short)f2bf(hi);
    return a | (b << 16);
}
__device__ __forceinline__ void gload16(const void* g, void* l) {
    __builtin_amdgcn_global_load_lds(
        (const __attribute__((address_space(1))) unsigned int*)g,
        (__attribute__((address_space(3))) unsigned int*)l, 16, 0, 0);
}

// ---------------------------------------------------------------------------
// prep_w: blocks 0..511 convert Wq/Wk/Wv/Wo to bf16 (Wq pre-scaled by
// 0.125*log2e); blocks 512..767 MT = M^T bf16 via LDS tile transpose.
// ---------------------------------------------------------------------------
__global__ __launch_bounds__(256) void prep_w(
    const float* __restrict__ M, const float* __restrict__ Wq,
    const float* __restrict__ Wk, const float* __restrict__ Wv,
    const float* __restrict__ Wo, __hip_bfloat16* __restrict__ wb)
{
    __hip_bfloat16* wsrc = wb;                 // 1536*512
    __hip_bfloat16* Wob  = wb + 786432;        // 512*512
    __hip_bfloat16* MT   = wb + 1048576;       // 512*512

    const int blk = blockIdx.x, t = threadIdx.x;
    if (blk < 512) {
        const int wi = blk >> 7;               // 0:Wq 1:Wk 2:Wv 3:Wo
        const int off = (blk & 127) * 2048 + t * 8;
        const float* src = (wi == 0) ? Wq : (wi == 1) ? Wk : (wi == 2) ? Wv : Wo;
        const float scale = (wi == 0) ? 0.18033688011112042f : 1.0f;
        const float4 f0 = *reinterpret_cast<const float4*>(src + off);
        const float4 f1 = *reinterpret_cast<const float4*>(src + off + 4);
        const float fv[8] = {f0.x, f0.y, f0.z, f0.w, f1.x, f1.y, f1.z, f1.w};
        union { short s[8]; bf16x8 v; } r;
#pragma unroll
        for (int j = 0; j < 8; ++j) r.s[j] = f2bf(fv[j] * scale);
        __hip_bfloat16* dst = (wi == 3) ? (Wob + off) : (wsrc + wi * 262144 + off);
        *reinterpret_cast<bf16x8*>(dst) = r.v;
    } else {
        __shared__ float tile[32][33];
        const int tt = blk - 512;              // 256 tiles
        const int e0 = (tt & 15) * 32, d0 = (tt >> 4) * 32;
        const int r = t >> 5, c = t & 31;
#pragma unroll
        for (int k = 0; k < 4; ++k)
            tile[r + k * 8][c] = M[(size_t)(e0 + r + k * 8) * 512 + d0 + c];
        __syncthreads();
#pragma unroll
        for (int k = 0; k < 4; ++k)
            MT[(size_t)(d0 + r + k * 8) * 512 + e0 + c] =
                __float2bfloat16(tile[c][r + k * 8]);
    }
}

// ---------------------------------------------------------------------------
// bias_k: qkvpart[dc][w*16+b][n] over 4 d-chunks of 128.
// ---------------------------------------------------------------------------
__global__ __launch_bounds__(256) void bias_k(
    const __hip_bfloat16* __restrict__ wsrc, const float* __restrict__ ts_emb,
    const int* __restrict__ te, float* __restrict__ qkvpart)
{
    const int blk = blockIdx.x;
    const int w16b = blk >> 2, dc = blk & 3;
    const int b = w16b & 15, w = w16b >> 4;
    const float* e = ts_emb + (size_t)te[b] * 512 + dc * 128;
#pragma unroll
    for (int rep = 0; rep < 2; ++rep) {
        const int n = threadIdx.x + rep * 256;
        const __hip_bfloat16* wr = wsrc + ((size_t)(w * 512 + n)) * 512 + dc * 128;
        float s = 0.f;
#pragma unroll 4
        for (int d8 = 0; d8 < 128; d8 += 8) {
            const bf16x8 wv8 = *reinterpret_cast<const bf16x8*>(wr + d8);
            const float4 e0 = *reinterpret_cast<const float4*>(e + d8);
            const float4 e1 = *reinterpret_cast<const float4*>(e + d8 + 4);
            s += bf2f(wv8[0]) * e0.x + bf2f(wv8[1]) * e0.y
               + bf2f(wv8[2]) * e0.z + bf2f(wv8[3]) * e0.w
               + bf2f(wv8[4]) * e1.x + bf2f(wv8[5]) * e1.y
               + bf2f(wv8[6]) * e1.z + bf2f(wv8[7]) * e1.w;
        }
        qkvpart[(size_t)dc * 24576 + (size_t)w16b * 512 + n] = s;
    }
}

// ---------------------------------------------------------------------------
// K1: conv1d + bias + pos-emb + GELU + LN -> n1 bf16 (B*S,512).
// ---------------------------------------------------------------------------
__global__ __launch_bounds__(256) void k1_conv_gelu_ln(
    const float* __restrict__ ts, const float* __restrict__ conv_w,
    const float* __restrict__ conv_b, const float* __restrict__ pe,
    const float* __restrict__ g1, const float* __restrict__ b1,
    __hip_bfloat16* __restrict__ n1)
{
    const int w = threadIdx.x >> 6, lane = threadIdx.x & 63;
    const int row = blockIdx.x * 4 + w;      // b*S + s
    const int b = row >> 10, s = row & 1023;
    const float4 x = *reinterpret_cast<const float4*>(ts + b * 4096 + s * 4);
    const int d0 = lane * 8;

    const float4 cb0 = *reinterpret_cast<const float4*>(conv_b + d0);
    const float4 cb1 = *reinterpret_cast<const float4*>(conv_b + d0 + 4);
    const float4 pe0 = *reinterpret_cast<const float4*>(pe + s * 512 + d0);
    const float4 pe1 = *reinterpret_cast<const float4*>(pe + s * 512 + d0 + 4);
    const float cbv[8] = {cb0.x, cb0.y, cb0.z, cb0.w, cb1.x, cb1.y, cb1.z, cb1.w};
    const float pev[8] = {pe0.x, pe0.y, pe0.z, pe0.w, pe1.x, pe1.y, pe1.z, pe1.w};

    float a[8];
    float sum = 0.f, sq = 0.f;
#pragma unroll
    for (int j = 0; j < 8; ++j) {
        const float4 wv = *reinterpret_cast<const float4*>(conv_w + (d0 + j) * 4);
        float v = x.x * wv.x + x.y * wv.y + x.z * wv.z + x.w * wv.w
                + cbv[j] + pev[j];
        v = 0.5f * v * (1.0f + erff(v * 0.70710678118654752f));
        a[j] = v; sum += v; sq += v * v;
    }
#pragma unroll
    for (int off = 1; off < 64; off <<= 1) {
        sum += __shfl_xor(sum, off);
        sq  += __shfl_xor(sq, off);
    }
    const float mean = sum * (1.0f / 512.0f);
    const float var  = (sq - 512.0f * mean * mean) * (1.0f / 511.0f);
    const float rstd = rsqrtf(var + 1e-5f);
    const float gg = g1[s], bb = b1[s];
    union { short sh[8]; bf16x8 v; } o;
#pragma unroll
    for (int j = 0; j < 8; ++j)
        o.sh[j] = f2bf(gg * ((a[j] - mean) * rstd) + bb);
    *reinterpret_cast<bf16x8*>(n1 + (size_t)row * 512 + d0) = o.v;
}

// ---------------------------------------------------------------------------
// GEMM: out[r][n] = sum_d A[r][d] * Wb[n][d]  (bf16 x bf16, K=512)
// BM=128 BN=128 BK=64, 4 waves (2x2). Double-buffered LDS, 2-phase
// (R9's measured-best structure).
// MODE 3: += bo[n], write BF16 row-major (Wo GEMM)
// MODE 5: fused QKV; w3 = Nb>>9 selects q/k/vT layout; += 4 qkvpart chunks
// MODE 6: plain bf16 row-major (weight compose)
// ---------------------------------------------------------------------------
template<int MODE>
__global__ __launch_bounds__(256, 2) void gemm_k(
    const __hip_bfloat16* __restrict__ A,
    const __hip_bfloat16* __restrict__ Wb,
    void* __restrict__ outp,
    const float* __restrict__ aux)
{
    __shared__ char lA[2][128 * 128];
    __shared__ char lB[2][128 * 128];

    const int t = threadIdx.x;
    const int lane = t & 63;
    const int w = t >> 6;
    const int wm = w & 1, wn = w >> 1;
    const int Rb = blockIdx.x * 128;
    const int Nb = blockIdx.y * 128;
    const int g = lane >> 4, lr = lane & 15;
    const int lrow = lane >> 3;
    const int coff = ((lane & 7) ^ lrow) * 8;

    const __hip_bfloat16* asrc = A  + (size_t)(Rb + lrow) * 512 + coff;
    const __hip_bfloat16* bsrc = Wb + (size_t)(Nb + lrow) * 512 + coff;

    f32x4 acc[4][4];
#pragma unroll
    for (int i = 0; i < 4; ++i)
#pragma unroll
        for (int j = 0; j < 4; ++j) acc[i][j] = {0.f, 0.f, 0.f, 0.f};

    auto stage = [&](int buf, int k0) {
#pragma unroll
        for (int i = 0; i < 4; ++i) {
            const int r0 = w * 32 + i * 8;
            gload16(asrc + (size_t)r0 * 512 + k0, &lA[buf][r0 * 128]);
        }
#pragma unroll
        for (int i = 0; i < 4; ++i) {
            const int r0 = w * 32 + i * 8;
            gload16(bsrc + (size_t)r0 * 512 + k0, &lB[buf][r0 * 128]);
        }
    };

    stage(0, 0);
    __syncthreads();

    for (int kt = 0; kt < 8; ++kt) {
        const int buf = kt & 1;
        if (kt < 7) stage(buf ^ 1, (kt + 1) * 64);
#pragma unroll
        for (int kk = 0; kk < 2; ++kk) {
            bf16x8 af[4], bfv[4];
            const int ch = kk * 4 + g;
#pragma unroll
            for (int mt = 0; mt < 4; ++mt) {
                const int row = wm * 64 + mt * 16 + lr;
                af[mt] = *reinterpret_cast<const bf16x8*>(
                    &lA[buf][row * 128 + ((ch ^ (row & 7)) << 4)]);
            }
#pragma unroll
            for (int nt = 0; nt < 4; ++nt) {
                const int row = wn * 64 + nt * 16 + lr;
                bfv[nt] = *reinterpret_cast<const bf16x8*>(
                    &lB[buf][row * 128 + ((ch ^ (row & 7)) << 4)]);
            }
#pragma unroll
            for (int mt = 0; mt < 4; ++mt)
#pragma unroll
                for (int nt = 0; nt < 4; ++nt)
                    acc[mt][nt] = __builtin_amdgcn_mfma_f32_16x16x32_bf16(
                        af[mt], bfv[nt], acc[mt][nt], 0, 0, 0);
        }
        __syncthreads();
    }

    const int w3 = Nb >> 9;   // block-uniform (MODE 5)
#pragma unroll
    for (int mt = 0; mt < 4; ++mt) {
#pragma unroll
        for (int nt = 0; nt < 4; ++nt) {
#pragma unroll
            for (int r = 0; r < 4; ++r) {
                const int R = Rb + wm * 64 + mt * 16 + 4 * g + r;
                const int N = Nb + wn * 64 + nt * 16 + lr;
                float v = acc[mt][nt][r];
                if (MODE == 5) {
                    const int Nl = N & 511;
                    const int b = R >> 10, s = R & 1023, h = Nl >> 6, c = Nl & 63;
                    const float* qp = aux + (size_t)(w3 * 16 + b) * 512 + Nl;
                    v += qp[0] + qp[24576] + qp[49152] + qp[73728];
                    __hip_bfloat16* base =
                        reinterpret_cast<__hip_bfloat16*>(outp) + (size_t)w3 * 8388608;
                    if (w3 == 2)
                        base[(((size_t)(b * 8 + h)) * 64 + c) * 1024 + s] =
                            __float2bfloat16(v);
                    else
                        base[(((size_t)(b * 8 + h)) * 1024 + s) * 64 + c] =
                            __float2bfloat16(v);
                } else if (MODE == 6) {
                    reinterpret_cast<__hip_bfloat16*>(outp)[(size_t)R * 512 + N] =
                        __float2bfloat16(v);
                } else {
                    reinterpret_cast<__hip_bfloat16*>(outp)[(size_t)R * 512 + N] =
                        __float2bfloat16(v + aux[N]);
                }
            }
        }
    }
}

// ---------------------------------------------------------------------------
// Flash attention (attn5, measured-best): block-shared LDS staging,
// transposed-score 32x32, permuted-k PV, exp2 domain, defer-max.
// 1024 blocks, 4/CU, big-tiles-first perm ordering.
// ---------------------------------------------------------------------------
__device__ __forceinline__ void write_strip(
    __hip_bfloat16* __restrict__ dstbase, const int jw0,
    const f32x16& o0, const f32x16& o1, const float lsum,
    const int l5, const int ln31)
{
    const float linv = 1.0f / lsum;
#pragma unroll
    for (int r = 0; r < 16; ++r) {
        const int jrow = (r & 3) + 8 * (r >> 2) + 4 * l5;
        const float rinv = __shfl(linv, jrow);
        __hip_bfloat16* dst = dstbase + (size_t)(jw0 + jrow) * 512;
        dst[ln31]      = __float2bfloat16(o0[r] * rinv);
        dst[32 + ln31] = __float2bfloat16(o1[r] * rinv);
    }
}

__global__ __launch_bounds__(256, 4) void attn5_k(
    const __hip_bfloat16* __restrict__ Qm,   // (B,H,S,64), pre-scaled
    const __hip_bfloat16* __restrict__ Km,   // (B,H,S,64)
    const __hip_bfloat16* __restrict__ Vt,   // (B,H,64,S)
    __hip_bfloat16* __restrict__ cat)        // (B,S,512)
{
    __shared__ char qbuf[2][4096];
    __shared__ char vbuf[2][4096];

    const int t = threadIdx.x, lane = t & 63, w = t >> 6;
    const int l5 = lane >> 5, ln31 = lane & 31;
    const int id = blockIdx.x;
    const int bh = id & 127;
    const int jb = (0x32451067u >> ((id >> 7) * 4)) & 7;
    const int b = bh >> 3, h = bh & 7;
    const int j0 = jb * 128 + w * 32;

    const __hip_bfloat16* Qh = Qm + (size_t)bh * (S_ * 64);
    const __hip_bfloat16* Kh = Km + (size_t)bh * (S_ * 64);
    const __hip_bfloat16* Vh = Vt + (size_t)bh * (64 * S_);

    bf16x8 kf[4];
#pragma unroll
    for (int kt = 0; kt < 4; ++kt)
        kf[kt] = *reinterpret_cast<const bf16x8*>(
            Kh + (size_t)(j0 + ln31) * 64 + kt * 16 + l5 * 8);

    f32x16 o0, o1;
#pragma unroll
    for (int r = 0; r < 16; ++r) { o0[r] = 0.f; o1[r] = 0.f; }
    float m = -3e38f, lsum = 0.f;

    const int last = jb * 4 + w;
    const int ntiles = jb * 4 + 4;

    const int q_row  = w * 8 + (lane >> 3);
    const int q_ch   = (lane & 7) ^ (lane >> 3);
    const int v_row  = w * 16 + (lane >> 2);
    const int v_ch   = (lane & 3) ^ ((lane >> 2) & 3) ^ ((lane >> 4) & 3);
    const __hip_bfloat16* qsrc = Qh + (size_t)q_row * 64 + q_ch * 8;
    const __hip_bfloat16* vsrc = Vh + (size_t)v_row * 1024 + v_ch * 8;

    auto stage = [&](int buf, int tile) {
        const int i0 = tile * 32;
        gload16(qsrc + (size_t)i0 * 64, &qbuf[buf][w * 1024]);
        gload16(vsrc + i0,              &vbuf[buf][w * 1024]);
    };

    stage(0, 0);
    __syncthreads();

    for (int tt = 0; tt < ntiles; ++tt) {
        const int buf = tt & 1;
        if (tt + 1 < ntiles) stage(buf ^ 1, tt + 1);
        if (tt <= last) {
            f32x16 sc;
#pragma unroll
            for (int r = 0; r < 16; ++r) sc[r] = 0.f;
            bf16x8 qf[4];
#pragma unroll
            for (int kt = 0; kt < 4; ++kt)
                qf[kt] = *reinterpret_cast<const bf16x8*>(
                    &qbuf[buf][ln31 * 128 + (((kt * 2 + l5) ^ (ln31 & 7)) << 4)]);
#pragma unroll
            for (int kt = 0; kt < 4; ++kt)
                sc = __builtin_amdgcn_mfma_f32_32x32x16_bf16(qf[kt], kf[kt], sc, 0, 0, 0);

            union u8 { bf16x4 h[2]; bf16x8 v; };
            u8 vf[2][2];
#pragma unroll
            for (int kt = 0; kt < 2; ++kt) {
#pragma unroll
                for (int dh = 0; dh < 2; ++dh) {
                    const int drow = ln31 + dh * 32;
                    const int swz = (drow & 3) ^ ((drow >> 2) & 3);
                    const int x0 = kt * 32 + 8 * l5;
#pragma unroll
                    for (int hp = 0; hp < 2; ++hp) {
                        const int x = x0 + hp * 16;
                        vf[kt][dh].h[hp] = *reinterpret_cast<const bf16x4*>(
                            &vbuf[buf][drow * 64 + (((x >> 4) ^ swz) << 4) + (x & 15)]);
                    }
                }
            }

            const bool diag = (tt == last);
            float p[16];
            float mx = -3e38f;
            if (diag) {
#pragma unroll
                for (int r = 0; r < 16; ++r) {
                    const int irow = (r & 3) + 8 * (r >> 2) + 4 * l5;
                    const float v = (irow > ln31) ? -3e38f : sc[r];
                    p[r] = v; mx = fmaxf(mx, v);
                }
            } else {
#pragma unroll
                for (int r = 0; r < 16; ++r) { p[r] = sc[r]; mx = fmaxf(mx, sc[r]); }
            }
            mx = fmaxf(mx, __shfl_xor(mx, 32));
            if (!__all(mx <= m + 8.0f)) {
                const float mn = fmaxf(m, mx);
                const float alpha = exp2f(m - mn);
                m = mn; lsum *= alpha;
#pragma unroll
                for (int r = 0; r < 16; ++r) {
                    const int jrow = (r & 3) + 8 * (r >> 2) + 4 * l5;
                    const float ar = __shfl(alpha, jrow);
                    o0[r] *= ar; o1[r] *= ar;
                }
            }
            float ps = 0.f;
#pragma unroll
            for (int r = 0; r < 16; ++r) { p[r] = exp2f(p[r] - m); ps += p[r]; }
            ps += __shfl_xor(ps, 32);
            lsum += ps;

            union { unsigned u[4]; bf16x8 v; } pa0, pa1;
            pa0.u[0] = pack_bf2(p[0],  p[1]);  pa0.u[1] = pack_bf2(p[2],  p[3]);
            pa0.u[2] = pack_bf2(p[4],  p[5]);  pa0.u[3] = pack_bf2(p[6],  p[7]);
            pa1.u[0] = pack_bf2(p[8],  p[9]);  pa1.u[1] = pack_bf2(p[10], p[11]);
            pa1.u[2] = pack_bf2(p[12], p[13]); pa1.u[3] = pack_bf2(p[14], p[15]);
            o0 = __builtin_amdgcn_mfma_f32_32x32x16_bf16(pa0.v, vf[0][0].v, o0, 0, 0, 0);
            o1 = __builtin_amdgcn_mfma_f32_32x32x16_bf16(pa0.v, vf[0][1].v, o1, 0, 0, 0);
            o0 = __builtin_amdgcn_mfma_f32_32x32x16_bf16(pa1.v, vf[1][0].v, o0, 0, 0, 0);
            o1 = __builtin_amdgcn_mfma_f32_32x32x16_bf16(pa1.v, vf[1][1].v, o1, 0, 0, 0);
        }
        __syncthreads();
    }

    __hip_bfloat16* dstbase = cat + (size_t)b * 1024 * 512 + h * 64;
    write_strip(dstbase, j0, o0, o1, lsum, l5, ln31);
}

// ---------------------------------------------------------------------------
// K5: residual (recompute conv) + LayerNorm over D, transposed store.
// outf is bf16.
// ---------------------------------------------------------------------------
__global__ __launch_bounds__(256) void k5_res_ln(
    const __hip_bfloat16* __restrict__ outf,
    const float* __restrict__ ts, const float* __restrict__ conv_w,
    const float* __restrict__ conv_b, const float* __restrict__ pe,
    const float* __restrict__ g2, const float* __restrict__ b2,
    float* __restrict__ out)         // (B,512,1024)
{
    __shared__ float tile[16 * 520];
    const int blk = blockIdx.x;
    const int b = blk >> 6, s0 = (blk & 63) * 16;
    const int t = threadIdx.x;
    const int sl = t >> 4, c = t & 15;
    const int s = s0 + sl;

    const float4 x = *reinterpret_cast<const float4*>(ts + b * 4096 + s * 4);
    float vals[32];
    float sum = 0.f, sq = 0.f;
#pragma unroll
    for (int j = 0; j < 32; ++j) {
        const int d = c + 16 * j;
        const float4 wv = *reinterpret_cast<const float4*>(conv_w + d * 4);
        const float conv = x.x * wv.x + x.y * wv.y + x.z * wv.z + x.w * wv.w
                         + conv_b[d] + pe[s * 512 + d];
        const float a = __bfloat162float(outf[(size_t)(b * 1024 + s) * 512 + d]) + conv;
        vals[j] = a; sum += a; sq += a * a;
    }
#pragma unroll
    for (int off = 1; off < 16; off <<= 1) {
        sum += __shfl_xor(sum, off);
        sq  += __shfl_xor(sq, off);
    }
    const float mean = sum * (1.0f / 512.0f);
    const float var  = (sq - 512.0f * mean * mean) * (1.0f / 511.0f);
    const float rstd = rsqrtf(var + 1e-5f);
    const float gg = g2[s], bb = b2[s];
#pragma unroll
    for (int j = 0; j < 32; ++j) {
        const int d = c + 16 * j;
        tile[sl * 520 + d] = gg * ((vals[j] - mean) * rstd) + bb;
    }
    __syncthreads();
#pragma unroll
    for (int q2 = 0; q2 < 2; ++q2) {
        const int d = t + q2 * 256;
        float buf[16];
#pragma unroll
        for (int sl2 = 0; sl2 < 16; ++sl2) buf[sl2] = tile[sl2 * 520 + d];
        float4* dst = reinterpret_cast<float4*>(
            out + ((size_t)b * 512 + d) * 1024 + s0);
        dst[0] = make_float4(buf[0],  buf[1],  buf[2],  buf[3]);
        dst[1] = make_float4(buf[4],  buf[5],  buf[6],  buf[7]);
        dst[2] = make_float4(buf[8],  buf[9],  buf[10], buf[11]);
        dst[3] = make_float4(buf[12], buf[13], buf[14], buf[15]);
    }
}

// ---------------------------------------------------------------------------
extern "C" void kernel_launch(void* const* d_in, const int* in_sizes, int n_in,
                              void* d_out, int out_size, void* d_ws, size_t ws_size,
                              hipStream_t stream)
{
    const float* ts     = (const float*)d_in[0];
    const int*   te     = (const int*)d_in[1];
    const float* conv_w = (const float*)d_in[2];
    const float* conv_b = (const float*)d_in[3];
    const float* pe     = (const float*)d_in[4];
    const float* ts_emb = (const float*)d_in[5];
    const float* g1     = (const float*)d_in[6];
    const float* b1     = (const float*)d_in[7];
    const float* M      = (const float*)d_in[8];
    const float* Wq     = (const float*)d_in[9];
    const float* Wk     = (const float*)d_in[10];
    const float* Wv     = (const float*)d_in[11];
    const float* Wo     = (const float*)d_in[12];
    const float* bo     = (const float*)d_in[13];
    const float* g2     = (const float*)d_in[14];
    const float* b2     = (const float*)d_in[15];

    char* ws = (char*)d_ws;
    __hip_bfloat16* wb     = (__hip_bfloat16*)(ws);                 // 3MB @0
    __hip_bfloat16* wsrc   = wb;                                    // 1536x512
    __hip_bfloat16* Wob    = wb + 786432;
    __hip_bfloat16* MT     = wb + 1048576;
    __hip_bfloat16* Wqkvp  = (__hip_bfloat16*)(ws + (2688ull << 10)); // 1.5MB
    float*          qkvpart= (float*)(ws + (4608ull << 10));        // 384KB
    __hip_bfloat16* n1     = (__hip_bfloat16*)(ws + ( 6ull << 20)); // 16MB @6
    __hip_bfloat16* cat    = n1;                                    // reuse @6
    __hip_bfloat16* q      = (__hip_bfloat16*)(ws + (22ull << 20)); // 16MB @22
    __hip_bfloat16* k      = (__hip_bfloat16*)(ws + (38ull << 20)); // 16MB @38
    __hip_bfloat16* vT     = (__hip_bfloat16*)(ws + (54ull << 20)); // 16MB @54
    __hip_bfloat16* outf   = (__hip_bfloat16*)(ws + (22ull << 20)); // 16MB @22 (q dead)

    prep_w<<<768, 256, 0, stream>>>(M, Wq, Wk, Wv, Wo, wb);
    bias_k<<<192, 256, 0, stream>>>(wsrc, ts_emb, te, qkvpart);
    gemm_k<6><<<dim3(12, 4), 256, 0, stream>>>(wsrc, MT, Wqkvp, nullptr);
    k1_conv_gelu_ln<<<4096, 256, 0, stream>>>(ts, conv_w, conv_b, pe, g1, b1, n1);
    gemm_k<5><<<dim3(128, 12), 256, 0, stream>>>(n1, Wqkvp, q, qkvpart);
    attn5_k<<<1024, 256, 0, stream>>>(q, k, vT, cat);
    gemm_k<3><<<dim3(128, 4), 256, 0, stream>>>(cat, Wob, outf, bo);
    k5_res_ln<<<1024, 256, 0, stream>>>(outf, ts, conv_w, conv_b, pe, g2, b2,
                                        (float*)d_out);
}